// Round 11
// baseline (600.098 us; speedup 1.0000x reference)
//
#include <hip/hip_runtime.h>

// EGNN conv: N=50000, E=800000, C=64.
// Round 11: round-10 bucket fusion with the counting-sort bug fixed: replica
// cursor index rep must be a PURE FUNCTION OF EDGE INDEX ((i>>8)&7), not of
// blockIdx (hist striped mod 560, scatter mod 768 -> per-(bucket,rep) counts
// mismatched -> segment overflow -> edges in wrong buckets, absmax 73).
// Structure: K1 = npre || hist || frag || pos4; K2 = scan; K3 = scatter
// (packed u32 (row&63)<<16|col); K4 = fused edge+node per 64-row bucket with
// LDS msg/coord accumulators (zero global aggregation atomics).

#define NN 50000
#define NE 800000
#define NB 782              // row buckets of 64
#define SC (NB * 8)         // replicated cursors
#define SCAN_T 256

typedef __attribute__((ext_vector_type(8))) short bf16x8;
typedef __attribute__((ext_vector_type(4))) short bf16x4;
typedef __attribute__((ext_vector_type(4))) float f32x4;

#define MFMA16(a, b, c) __builtin_amdgcn_mfma_f32_16x16x32_bf16(a, b, c, 0, 0, 0)

__device__ __forceinline__ unsigned short f2b(float x) {
    union { float f; unsigned u; } v; v.f = x;
    return (unsigned short)((v.u + 0x8000u) >> 16);
}
__device__ __forceinline__ float b2f(unsigned short b) {
    union { unsigned u; float f; } v; v.u = ((unsigned)b) << 16; return v.f;
}
__device__ __forceinline__ float silu_f(float x) {
    return x * __builtin_amdgcn_rcpf(1.0f + __expf(-x));
}

// wfrag layout (40 frags x 512 bf16): 0..7 We2, 8..15 Wc1, 16..31 Wn1, 32..39 Wn2.

// ---------------- K1: npre || hist || frag || pos4 ----------------

#define B1_NPRE 782
#define B1_HIST 560
#define B1_FRAG 10
#define B1_POS4 8
#define K1_GRID (B1_NPRE + B1_HIST + B1_FRAG + B1_POS4)

__global__ __launch_bounds__(256, 4) void prep1_kernel(
    const int* __restrict__ ei, const float* __restrict__ h,
    const float* __restrict__ pos,
    const float* __restrict__ We1, const float* __restrict__ be1,
    const float* __restrict__ We2, const float* __restrict__ Wc1,
    const float* __restrict__ Wn1, const float* __restrict__ Wn2,
    unsigned short* __restrict__ a1r, unsigned short* __restrict__ a1c,
    unsigned short* __restrict__ wfrag, int* __restrict__ cursor,
    float4* __restrict__ pos4)
{
    __shared__ __align__(16) unsigned short sH[64][72];
    __shared__ __align__(16) unsigned short sT[4][16][72];
    const int b = blockIdx.x, tid = threadIdx.x;
    const int lane = tid & 63, w = tid >> 6;
    const int li = lane & 15, lg = lane >> 4;

    if (b < B1_NPRE) {
        // node_pre: a1r = h@We1[0:64]+be1, a1c = h@We1[64:128] (bf16).
        const int t = b;
        const int c4 = lane & 15, rsub = lane >> 4;
#pragma unroll
        for (int pass = 0; pass < 4; ++pass) {
            const int n_loc = w * 16 + pass * 4 + rsub;
            const int n = t * 64 + n_loc;
            float4 hv = make_float4(0.f, 0.f, 0.f, 0.f);
            if (n < NN) hv = *(const float4*)&h[(size_t)n * 64 + c4 * 4];
            bf16x4 hp;
            hp[0] = (short)f2b(hv.x); hp[1] = (short)f2b(hv.y);
            hp[2] = (short)f2b(hv.z); hp[3] = (short)f2b(hv.w);
            *(bf16x4*)&sH[n_loc][c4 * 4] = hp;   // wave-private rows
        }
        float be1v[4];
#pragma unroll
        for (int ni = 0; ni < 4; ++ni) be1v[ni] = be1[ni * 16 + li];

#pragma unroll
        for (int half = 0; half < 2; ++half) {
            const float* W = We1 + half * 64 * 64;
            unsigned short* out = half ? a1c : a1r;
            f32x4 acc[4];
#pragma unroll
            for (int ni = 0; ni < 4; ++ni) acc[ni] = (f32x4)(0.0f);
#pragma unroll
            for (int ks = 0; ks < 2; ++ks) {
                const bf16x8 afr = *(const bf16x8*)&sH[w * 16 + li][ks * 32 + (lg << 3)];
#pragma unroll
                for (int ni = 0; ni < 4; ++ni) {
                    const int n = ni * 16 + li;
                    const int kb = ks * 32 + (lg << 3);
                    bf16x8 bfr;
#pragma unroll
                    for (int j = 0; j < 8; ++j) bfr[j] = (short)f2b(W[(kb + j) * 64 + n]);
                    acc[ni] = MFMA16(afr, bfr, acc[ni]);
                }
            }
#pragma unroll
            for (int ni = 0; ni < 4; ++ni)
#pragma unroll
                for (int reg = 0; reg < 4; ++reg)
                    sT[w][lg * 4 + reg][ni * 16 + li] =
                        f2b(acc[ni][reg] + (half ? 0.f : be1v[ni]));
#pragma unroll
            for (int pass = 0; pass < 2; ++pass) {
                const int rr = pass * 8 + (lane >> 3);
                const int n = t * 64 + w * 16 + rr;
                const bf16x8 v = *(const bf16x8*)&sT[w][rr][(lane & 7) * 8];
                if (n < NN) *(bf16x8*)&out[(size_t)n * 64 + (lane & 7) * 8] = v;
            }
        }
    } else if (b < B1_NPRE + B1_HIST) {
        int i = (b - B1_NPRE) * 256 + tid;
        for (; i < NE; i += B1_HIST * 256)
            atomicAdd(&cursor[(ei[i] >> 6) * 8 + ((i >> 8) & 7)], 1);  // rep = f(i)!
    } else if (b < B1_NPRE + B1_HIST + B1_FRAG) {
        const int f = (b - B1_NPRE - B1_HIST) * 4 + w;  // 0..39
        const float* W; int g;
        if (f < 8)       { W = We2; g = f; }
        else if (f < 16) { W = Wc1; g = f - 8; }
        else if (f < 32) { W = Wn1; g = f - 16; }
        else             { W = Wn2; g = f - 32; }
        const int ks = g >> 2, ni = g & 3;
        const int n = ni * 16 + li, kb = ks * 32 + (lg << 3);
        bf16x8 v;
#pragma unroll
        for (int j = 0; j < 8; ++j) v[j] = (short)f2b(W[(kb + j) * 64 + n]);
        *(bf16x8*)(wfrag + (size_t)f * 512 + lane * 8) = v;
    } else {
        int i = (b - B1_NPRE - B1_HIST - B1_FRAG) * 256 + tid;
        for (; i < NN; i += B1_POS4 * 256)
            pos4[i] = make_float4(pos[3 * i], pos[3 * i + 1], pos[3 * i + 2], 0.f);
    }
}

// ---------------- K2: scan cursor[SC] (1 block), emit bucket_off ----------------

__global__ void scan_kernel(int* __restrict__ cur, int* __restrict__ bucket_off) {
    __shared__ int wsum[4];
    const int t = threadIdx.x, lane = t & 63, wid = t >> 6;
    int local[25];
    const int base = t * 25;
    int s = 0;
#pragma unroll
    for (int i = 0; i < 25; ++i) {
        const int v = (base + i < SC) ? cur[base + i] : 0;
        local[i] = v;
        s += v;
    }
    int inc = s;
#pragma unroll
    for (int d = 1; d < 64; d <<= 1) {
        const int o = __shfl_up(inc, d, 64);
        if (lane >= d) inc += o;
    }
    if (lane == 63) wsum[wid] = inc;
    __syncthreads();
    int add = 0;
#pragma unroll
    for (int i = 0; i < 4; ++i) if (i < wid) add += wsum[i];
    int run = add + inc - s;
#pragma unroll
    for (int i = 0; i < 25; ++i) {
        const int slot = base + i;
        if (slot < SC) {
            cur[slot] = run;
            if ((slot & 7) == 0) bucket_off[slot >> 3] = run;
        }
        run += local[i];
    }
    if (t == 0) bucket_off[NB] = NE;
}

// ---------------- K3: scatter packed u32 into bucket segments ----------------

__global__ __launch_bounds__(256, 4) void scatter_kernel(
    const int* __restrict__ ei, int* __restrict__ cursor,
    unsigned* __restrict__ ebuf)
{
    int i = blockIdx.x * 256 + threadIdx.x;
    const int stride = gridDim.x * 256;
    for (; i < NE; i += stride) {
        const int r = ei[i];
        const int c = ei[NE + i];
        const int p = atomicAdd(&cursor[(r >> 6) * 8 + ((i >> 8) & 7)], 1);  // rep = f(i)!
        ebuf[p] = ((unsigned)(r & 63) << 16) | (unsigned)c;
    }
}

// ---------------- K4: fused edge + node, block = bucket ----------------

__global__ __launch_bounds__(256, 4) void fused_kernel(
    const float4* __restrict__ pos4, const unsigned* __restrict__ ebuf,
    const int* __restrict__ bucket_off,
    const unsigned short* __restrict__ a1r, const unsigned short* __restrict__ a1c,
    const float* __restrict__ We1,  // row 128 = dist weights
    const unsigned short* __restrict__ wfrag,
    const float* __restrict__ h,
    const float* __restrict__ be2, const float* __restrict__ bc1,
    const float* __restrict__ Wc2, const float* __restrict__ bc2,
    const float* __restrict__ bn1, const float* __restrict__ bn2,
    float* __restrict__ h_out, float* __restrict__ pos_out)
{
    __shared__ __align__(16) char smem[34816];
    float* msgAcc   = (float*)smem;                       // [64][64] f32, 16384 B
    float* coordAcc = (float*)(smem + 16384);             // [64][4]  f32, 1024 B
    unsigned short (*sA)[80] = (unsigned short (*)[80])(smem + 17408);  // 10240 B
    float4* sdr = (float4*)(smem + 27648);                // 1024 B
    float*  scw = (float*)(smem + 28672);                 // 256 B
    unsigned short* ssc  = (unsigned short*)(smem + 28928);  // 128 B
    unsigned short* ssrl = (unsigned short*)(smem + 29056);  // 128 B
    unsigned short (*nodeSA)[136] = (unsigned short (*)[136])(smem + 17408); // node phase

    const int tid = threadIdx.x;
    const int lane = tid & 63, w = tid >> 6;
    const int li = lane & 15, lg = lane >> 4;
    const int bucket = blockIdx.x;
    const int e0 = w * 16;

    // zero LDS accumulators
#pragma unroll
    for (int k = 0; k < 17; ++k) {
        const int i = k * 256 + tid;
        if (i < 64 * 64 + 64 * 4)
            ((float*)smem)[i] = 0.0f;   // msgAcc then coordAcc (contiguous)
    }

    const int gbeg = bucket_off[bucket];
    const int gend = bucket_off[bucket + 1];

    const int c8 = lane & 7, eo = lane >> 3;
    float w1d8[8];
    {
        const float* wd = We1 + 128 * 64 + c8 * 8;
        const float4 wa = *(const float4*)wd;
        const float4 wb = *(const float4*)(wd + 4);
        w1d8[0] = wa.x; w1d8[1] = wa.y; w1d8[2] = wa.z; w1d8[3] = wa.w;
        w1d8[4] = wb.x; w1d8[5] = wb.y; w1d8[6] = wb.z; w1d8[7] = wb.w;
    }
    float be2v[4], bc1v[4], wc2v[4];
#pragma unroll
    for (int ni = 0; ni < 4; ++ni) {
        be2v[ni] = be2[ni * 16 + li];
        bc1v[ni] = bc1[ni * 16 + li];
        wc2v[ni] = Wc2[ni * 16 + li];
    }
    const float bc2s = bc2[0];
    __syncthreads();  // accumulators zeroed

    // -------- edge tile loop (no barriers inside) --------
    for (int tb = gbeg; tb < gend; tb += 64) {
        // phase 0 (lanes 0-15 of each wave): meta for own 16 edges
        if (lane < 16) {
            const int e = e0 + lane;
            const int ge = tb + e;
            const unsigned packed = (ge < gend) ? ebuf[ge] : 0u;
            const int col = (int)(packed & 0xffffu);
            const int rl  = (int)((packed >> 16) & 63u);
            const float4 pr = pos4[bucket * 64 + rl];
            const float4 pc = pos4[col];
            const float rx = pr.x - pc.x, ry = pr.y - pc.y, rz = pr.z - pc.z;
            ssc[e] = (unsigned short)col;
            ssrl[e] = (unsigned short)rl;
            sdr[e] = make_float4(rx, ry, rz, rx * rx + ry * ry + rz * rz);
        }
        // phase 2: stage m for own 16 edges (wave-private sA rows)
#pragma unroll
        for (int hh = 0; hh < 2; ++hh) {
            const int e = e0 + hh * 8 + eo;
            const int rl = ssrl[e];
            const int ce = ssc[e];
            const float dv = sdr[e].w;
            const bf16x8 ar = *(const bf16x8*)(a1r + (size_t)(bucket * 64 + rl) * 64 + c8 * 8);
            const bf16x8 ac = *(const bf16x8*)(a1c + (size_t)ce * 64 + c8 * 8);
            bf16x8 out;
#pragma unroll
            for (int j = 0; j < 8; ++j) {
                const float m = b2f((unsigned short)ar[j]) + b2f((unsigned short)ac[j])
                              + dv * w1d8[j];
                out[j] = (short)f2b(silu_f(m));
            }
            *(bf16x8*)&sA[e][c8 * 8] = out;
        }
        // phase 3: GEMM2 (msg_pre = m @ We2)
        f32x4 acc[4];
#pragma unroll
        for (int ni = 0; ni < 4; ++ni) acc[ni] = (f32x4)(0.0f);
#pragma unroll
        for (int ks = 0; ks < 2; ++ks) {
            const bf16x8 af = *(const bf16x8*)&sA[e0 + li][ks * 32 + (lg << 3)];
#pragma unroll
            for (int ni = 0; ni < 4; ++ni) {
                const bf16x8 bf = *(const bf16x8*)(wfrag + (size_t)(ks * 4 + ni) * 512 + lane * 8);
                acc[ni] = MFMA16(af, bf, acc[ni]);
            }
        }
        // phase 4: msg = silu(msg_pre + be2) -> sA (own rows)
#pragma unroll
        for (int ni = 0; ni < 4; ++ni)
#pragma unroll
            for (int reg = 0; reg < 4; ++reg)
                sA[e0 + lg * 4 + reg][ni * 16 + li] = f2b(silu_f(acc[ni][reg] + be2v[ni]));
        // phase 5: msg -> LDS accumulator (ds_add per edge; wave-uniform guard)
#pragma unroll 4
        for (int j = 0; j < 16; ++j) {
            if (tb + e0 + j < gend) {
                const int rl = ssrl[e0 + j];
                atomicAdd(&msgAcc[rl * 64 + lane], b2f(sA[e0 + j][lane]));
            }
        }
        // phase 6: GEMM3 (t = msg @ Wc1)
        f32x4 a3[4];
#pragma unroll
        for (int ni = 0; ni < 4; ++ni) a3[ni] = (f32x4)(0.0f);
#pragma unroll
        for (int ks = 0; ks < 2; ++ks) {
            const bf16x8 af = *(const bf16x8*)&sA[e0 + li][ks * 32 + (lg << 3)];
#pragma unroll
            for (int ni = 0; ni < 4; ++ni) {
                const bf16x8 bf = *(const bf16x8*)(wfrag + (size_t)(8 + ks * 4 + ni) * 512 + lane * 8);
                a3[ni] = MFMA16(af, bf, a3[ni]);
            }
        }
        // epilogue: cw[edge] = sum_c silu(t+bc1)[c] * Wc2[c]
        float sv[4];
#pragma unroll
        for (int reg = 0; reg < 4; ++reg) {
            float s = 0.0f;
#pragma unroll
            for (int ni = 0; ni < 4; ++ni)
                s += silu_f(a3[ni][reg] + bc1v[ni]) * wc2v[ni];
            sv[reg] = s;
        }
#pragma unroll
        for (int m = 1; m < 16; m <<= 1)
#pragma unroll
            for (int reg = 0; reg < 4; ++reg) sv[reg] += __shfl_xor(sv[reg], m, 64);
        if (li == 0) {
            float4 cv = make_float4(sv[0] + bc2s, sv[1] + bc2s, sv[2] + bc2s, sv[3] + bc2s);
            *(float4*)&scw[e0 + lg * 4] = cv;
        }
        // phase 7: coord -> LDS accumulator (same-wave scw/sdr/ssrl reads)
        if (lane < 16) {
            const int e = e0 + lane;
            if (tb + e < gend) {
                const float cw = scw[e];
                const float4 dr = sdr[e];
                const int rl = ssrl[e];
                atomicAdd(&coordAcc[rl * 4 + 0], dr.x * cw);
                atomicAdd(&coordAcc[rl * 4 + 1], dr.y * cw);
                atomicAdd(&coordAcc[rl * 4 + 2], dr.z * cw);
            }
        }
    }
    __syncthreads();  // msgAcc/coordAcc complete

    // -------- pos_out for own 64 rows --------
    if (tid < 192) {
        const int rr = tid / 3, d = tid - rr * 3;
        const int n = bucket * 64 + rr;
        if (n < NN) {
            const float base_p = (&pos4[n].x)[d];
            pos_out[n * 3 + d] = base_p + coordAcc[rr * 4 + d];
        }
    }

    // -------- node MLP: h_out = silu([h|msg]@Wn1+bn1)@Wn2+bn2 --------
    float bn1v[4], bn2v[4];
#pragma unroll
    for (int ni = 0; ni < 4; ++ni) {
        bn1v[ni] = bn1[ni * 16 + li];
        bn2v[ni] = bn2[ni * 16 + li];
    }
#pragma unroll
    for (int pass = 0; pass < 8; ++pass) {
        const int idx = pass * 64 + lane;
        const int n_loc = w * 16 + (idx >> 5);
        const int c4 = idx & 31;
        const int n = bucket * 64 + n_loc;
        float4 v;
        if (c4 < 16) {
            v = make_float4(0.f, 0.f, 0.f, 0.f);
            if (n < NN) v = *(const float4*)&h[(size_t)n * 64 + c4 * 4];
        } else {
            v = *(const float4*)&msgAcc[n_loc * 64 + (c4 - 16) * 4];
        }
        bf16x4 p;
        p[0] = (short)f2b(v.x); p[1] = (short)f2b(v.y);
        p[2] = (short)f2b(v.z); p[3] = (short)f2b(v.w);
        *(bf16x4*)&nodeSA[n_loc][c4 * 4] = p;
    }
    // GEMM1: K=128
    f32x4 acc[4];
#pragma unroll
    for (int ni = 0; ni < 4; ++ni) acc[ni] = (f32x4)(0.0f);
#pragma unroll
    for (int ks = 0; ks < 4; ++ks) {
        const bf16x8 afr = *(const bf16x8*)&nodeSA[w * 16 + li][ks * 32 + (lg << 3)];
#pragma unroll
        for (int ni = 0; ni < 4; ++ni) {
            const bf16x8 bfr = *(const bf16x8*)(wfrag + (size_t)(16 + ks * 4 + ni) * 512 + lane * 8);
            acc[ni] = MFMA16(afr, bfr, acc[ni]);
        }
    }
#pragma unroll
    for (int ni = 0; ni < 4; ++ni)
#pragma unroll
        for (int reg = 0; reg < 4; ++reg)
            nodeSA[w * 16 + lg * 4 + reg][ni * 16 + li] = f2b(silu_f(acc[ni][reg] + bn1v[ni]));
    // GEMM2: K=64
    f32x4 a2[4];
#pragma unroll
    for (int ni = 0; ni < 4; ++ni) a2[ni] = (f32x4)(0.0f);
#pragma unroll
    for (int ks = 0; ks < 2; ++ks) {
        const bf16x8 afr = *(const bf16x8*)&nodeSA[w * 16 + li][ks * 32 + (lg << 3)];
#pragma unroll
        for (int ni = 0; ni < 4; ++ni) {
            const bf16x8 bfr = *(const bf16x8*)(wfrag + (size_t)(32 + ks * 4 + ni) * 512 + lane * 8);
            a2[ni] = MFMA16(afr, bfr, a2[ni]);
        }
    }
#pragma unroll
    for (int ni = 0; ni < 4; ++ni)
#pragma unroll
        for (int reg = 0; reg < 4; ++reg) {
            const int n = bucket * 64 + w * 16 + lg * 4 + reg;
            if (n < NN) h_out[(size_t)n * 64 + ni * 16 + li] = a2[ni][reg] + bn2v[ni];
        }
}

// ---------------- launch ----------------

extern "C" void kernel_launch(void* const* d_in, const int* in_sizes, int n_in,
                              void* d_out, int out_size, void* d_ws, size_t ws_size,
                              hipStream_t stream) {
    const float* h   = (const float*)d_in[0];
    const float* pos = (const float*)d_in[1];
    const int*   ei  = (const int*)d_in[2];
    const float* We1 = (const float*)d_in[3];
    const float* be1 = (const float*)d_in[4];
    const float* We2 = (const float*)d_in[5];
    const float* be2 = (const float*)d_in[6];
    const float* Wc1 = (const float*)d_in[7];
    const float* bc1 = (const float*)d_in[8];
    const float* Wc2 = (const float*)d_in[9];
    const float* bc2 = (const float*)d_in[10];
    const float* Wn1 = (const float*)d_in[11];
    const float* bn1 = (const float*)d_in[12];
    const float* Wn2 = (const float*)d_in[13];
    const float* bn2 = (const float*)d_in[14];

    // workspace layout (~17 MB)
    char* ws = (char*)d_ws;
    unsigned short* a1r   = (unsigned short*)(ws);              // 6,400,000 B
    unsigned short* a1c   = (unsigned short*)(ws + 6400000);    // 6,400,000 B
    unsigned short* wfrag = (unsigned short*)(ws + 12800000);   // 40,960 B
    unsigned*       ebuf  = (unsigned*)(ws + 12840960);         // 3,200,000 B
    int*       cursor     = (int*)(ws + 16040960);              // SC*4 = 25,024 B
    int*       bucket_off = (int*)(ws + 16066048);              // (NB+1)*4 B
    float4*    pos4       = (float4*)(ws + 16069184);           // 800,000 B

    float* h_out   = (float*)d_out;
    float* pos_out = h_out + (size_t)NN * 64;

    hipMemsetAsync(cursor, 0, (size_t)SC * sizeof(int), stream);
    prep1_kernel<<<K1_GRID, 256, 0, stream>>>(ei, h, pos, We1, be1, We2, Wc1, Wn1, Wn2,
                                              a1r, a1c, wfrag, cursor, pos4);
    scan_kernel<<<1, SCAN_T, 0, stream>>>(cursor, bucket_off);
    scatter_kernel<<<768, 256, 0, stream>>>(ei, cursor, ebuf);
    fused_kernel<<<NB, 256, 0, stream>>>(pos4, ebuf, bucket_off, a1r, a1c, We1, wfrag,
                                         h, be2, bc1, Wc2, bc2, bn1, bn2,
                                         h_out, pos_out);
}

// Round 12
// 307.750 us; speedup vs baseline: 1.9500x; 1.9500x over previous
//
#include <hip/hip_runtime.h>

// EGNN conv: N=50000, E=800000, C=64.
// Round 12: best-measured skeleton (round 7, 302us) + validated pieces:
// K1 = hist || frag(56 incl We1) || msg-zero || pos-copy/pos4; K2 = scan
// (emits row_ptr); K3 = npre(reads We1 frags from wfrag) || scatter-u16 ||
// srow-expand; K4 = round-9 edge kernel (68us, 12500 blocks); K5 = node.
// Round-11 lesson: bucket fusion collapsed TLP (782 blocks x serial 16-tile
// chain -> 431us @ VALU 12%); many independent blocks ARE the latency hiding.

#define NN 50000
#define NE 800000
#define ETILE 12500         // NE/64
#define NTILE 782           // ceil(NN/64)
#define SCAN_PAD 53248      // 1024*52

typedef __attribute__((ext_vector_type(8))) short bf16x8;
typedef __attribute__((ext_vector_type(4))) short bf16x4;
typedef __attribute__((ext_vector_type(4))) float f32x4;

#define MFMA16(a, b, c) __builtin_amdgcn_mfma_f32_16x16x32_bf16(a, b, c, 0, 0, 0)

__device__ __forceinline__ unsigned short f2b(float x) {
    union { float f; unsigned u; } v; v.f = x;
    return (unsigned short)((v.u + 0x8000u) >> 16);
}
__device__ __forceinline__ float b2f(unsigned short b) {
    union { unsigned u; float f; } v; v.u = ((unsigned)b) << 16; return v.f;
}
__device__ __forceinline__ float silu_f(float x) {
    return x * __builtin_amdgcn_rcpf(1.0f + __expf(-x));
}

// wfrag layout (56 frags x 512 bf16): 0..7 We2, 8..15 Wc1, 16..31 Wn1,
// 32..39 Wn2, 40..47 We1[0:64], 48..55 We1[64:128].

// ---------------- K1: hist || frag || zero || copy ----------------

#define B1_HIST 560
#define B1_FRAG 14
#define B1_ZERO 176
#define B1_COPY 18
#define K1_GRID (B1_HIST + B1_FRAG + B1_ZERO + B1_COPY)

__global__ __launch_bounds__(256, 4) void prep1_kernel(
    const int* __restrict__ ei, const float* __restrict__ pos,
    const float* __restrict__ We1, const float* __restrict__ We2,
    const float* __restrict__ Wc1, const float* __restrict__ Wn1,
    const float* __restrict__ Wn2,
    unsigned short* __restrict__ wfrag, int* __restrict__ cursor,
    float* __restrict__ msg_agg, float* __restrict__ pos_out,
    float4* __restrict__ pos4)
{
    const int b = blockIdx.x, tid = threadIdx.x;
    if (b < B1_HIST) {
        int i = b * 256 + tid;
        for (; i < NE; i += B1_HIST * 256) atomicAdd(&cursor[ei[i]], 1);
    } else if (b < B1_HIST + B1_FRAG) {
        const int lane = tid & 63, w = tid >> 6;
        const int li = lane & 15, lg = lane >> 4;
        const int f = (b - B1_HIST) * 4 + w;  // 0..55
        const float* W; int g;
        if (f < 8)       { W = We2; g = f; }
        else if (f < 16) { W = Wc1; g = f - 8; }
        else if (f < 32) { W = Wn1; g = f - 16; }
        else if (f < 40) { W = Wn2; g = f - 32; }
        else if (f < 48) { W = We1; g = f - 40; }
        else             { W = We1 + 64 * 64; g = f - 48; }
        const int ks = g >> 2, ni = g & 3;
        const int n = ni * 16 + li, kb = ks * 32 + (lg << 3);
        bf16x8 v;
#pragma unroll
        for (int j = 0; j < 8; ++j) v[j] = (short)f2b(W[(kb + j) * 64 + n]);
        *(bf16x8*)(wfrag + (size_t)f * 512 + lane * 8) = v;
    } else if (b < B1_HIST + B1_FRAG + B1_ZERO) {
        float4* dst = (float4*)msg_agg;
        int i = (b - B1_HIST - B1_FRAG) * 256 + tid;
        for (; i < NN * 16; i += B1_ZERO * 256) dst[i] = make_float4(0.f, 0.f, 0.f, 0.f);
    } else {
        int i = (b - B1_HIST - B1_FRAG - B1_ZERO) * 256 + tid;
        for (; i < 37500 + NN; i += B1_COPY * 256) {
            if (i < 37500) {
                ((float4*)pos_out)[i] = ((const float4*)pos)[i];
            } else {
                const int n = i - 37500;
                pos4[n] = make_float4(pos[3 * n], pos[3 * n + 1], pos[3 * n + 2], 0.f);
            }
        }
    }
}

// ---------------- K2: single-block scan; writes cursor AND row_ptr ----------------

__global__ void scan_kernel(int* __restrict__ cur, int* __restrict__ row_ptr) {
    __shared__ int wsum[16];
    const int t = threadIdx.x;
    const int lane = t & 63, wid = t >> 6;
    int4 v[13];
    const int4* src = (const int4*)cur + t * 13;
#pragma unroll
    for (int i = 0; i < 13; ++i) v[i] = src[i];
    int local[52];
#pragma unroll
    for (int i = 0; i < 13; ++i) {
        local[4 * i + 0] = v[i].x; local[4 * i + 1] = v[i].y;
        local[4 * i + 2] = v[i].z; local[4 * i + 3] = v[i].w;
    }
    int s = 0;
#pragma unroll
    for (int i = 0; i < 52; ++i) s += local[i];
    int inc = s;
#pragma unroll
    for (int d = 1; d < 64; d <<= 1) {
        const int o = __shfl_up(inc, d, 64);
        if (lane >= d) inc += o;
    }
    if (lane == 63) wsum[wid] = inc;
    __syncthreads();
    if (t == 0) {
        int run = 0;
#pragma unroll
        for (int i = 0; i < 16; ++i) { const int tmp = wsum[i]; wsum[i] = run; run += tmp; }
    }
    __syncthreads();
    int run = wsum[wid] + inc - s;
    const int base = t * 52;
#pragma unroll
    for (int i = 0; i < 52; ++i) {
        const int idx = base + i;
        if (idx < NN) { cur[idx] = run; row_ptr[idx] = run; }
        run += local[i];
    }
    if (t == 1023) row_ptr[NN] = run;  // == NE
}

// ---------------- K3: npre || scatter(u16 col) || srow expand ----------------

#define B3_NPRE 782
#define B3_SCAT 512
#define B3_EXP 196
#define K3_GRID (B3_NPRE + B3_SCAT + B3_EXP)

__global__ __launch_bounds__(256, 4) void prep2_kernel(
    const float* __restrict__ h, const float* __restrict__ be1,
    const int* __restrict__ ei, int* __restrict__ cursor,
    const int* __restrict__ row_ptr,
    const unsigned short* __restrict__ wfrag,
    unsigned short* __restrict__ a1r, unsigned short* __restrict__ a1c,
    unsigned short* __restrict__ scol, unsigned short* __restrict__ srow)
{
    __shared__ __align__(16) unsigned short sH[64][72];
    __shared__ __align__(16) unsigned short sT[4][16][72];
    const int b = blockIdx.x, tid = threadIdx.x;
    if (b < B3_NPRE) {
        // node_pre: a1r = h@We1[0:64]+be1, a1c = h@We1[64:128] (bf16).
        // One 64-node tile per block; wave w owns rows [w*16, w*16+16).
        // We1 B-frags come from wfrag (built by K1 -- no race, K1 precedes K3).
        const int lane = tid & 63, w = tid >> 6;
        const int li = lane & 15, lg = lane >> 4;
        const int t = b;
        const int c4 = lane & 15, rsub = lane >> 4;
#pragma unroll
        for (int pass = 0; pass < 4; ++pass) {
            const int n_loc = w * 16 + pass * 4 + rsub;
            const int n = t * 64 + n_loc;
            float4 hv = make_float4(0.f, 0.f, 0.f, 0.f);
            if (n < NN) hv = *(const float4*)&h[(size_t)n * 64 + c4 * 4];
            bf16x4 hp;
            hp[0] = (short)f2b(hv.x); hp[1] = (short)f2b(hv.y);
            hp[2] = (short)f2b(hv.z); hp[3] = (short)f2b(hv.w);
            *(bf16x4*)&sH[n_loc][c4 * 4] = hp;   // wave-private rows
        }
        float be1v[4];
#pragma unroll
        for (int ni = 0; ni < 4; ++ni) be1v[ni] = be1[ni * 16 + li];

#pragma unroll
        for (int half = 0; half < 2; ++half) {
            unsigned short* out = half ? a1c : a1r;
            f32x4 acc[4];
#pragma unroll
            for (int ni = 0; ni < 4; ++ni) acc[ni] = (f32x4)(0.0f);
#pragma unroll
            for (int ks = 0; ks < 2; ++ks) {
                const bf16x8 afr = *(const bf16x8*)&sH[w * 16 + li][ks * 32 + (lg << 3)];
#pragma unroll
                for (int ni = 0; ni < 4; ++ni) {
                    const bf16x8 bfr = *(const bf16x8*)(wfrag +
                        (size_t)(40 + half * 8 + ks * 4 + ni) * 512 + lane * 8);
                    acc[ni] = MFMA16(afr, bfr, acc[ni]);
                }
            }
            // transpose via wave-private sT, then coalesced dwordx4 stores
#pragma unroll
            for (int ni = 0; ni < 4; ++ni)
#pragma unroll
                for (int reg = 0; reg < 4; ++reg)
                    sT[w][lg * 4 + reg][ni * 16 + li] =
                        f2b(acc[ni][reg] + (half ? 0.f : be1v[ni]));
#pragma unroll
            for (int pass = 0; pass < 2; ++pass) {
                const int rr = pass * 8 + (lane >> 3);
                const int n = t * 64 + w * 16 + rr;
                const bf16x8 v = *(const bf16x8*)&sT[w][rr][(lane & 7) * 8];
                if (n < NN) *(bf16x8*)&out[(size_t)n * 64 + (lane & 7) * 8] = v;
            }
        }
    } else if (b < B3_NPRE + B3_SCAT) {
        int i = (b - B3_NPRE) * 256 + tid;
        for (; i < NE; i += B3_SCAT * 256) {
            const int r = ei[i];
            const int c = ei[NE + i];
            const int p = atomicAdd(&cursor[r], 1);
            scol[p] = (unsigned short)c;
        }
    } else {
        const int r = (b - B3_NPRE - B3_SCAT) * 256 + tid;
        if (r < NN) {
            const int s = row_ptr[r], e2 = row_ptr[r + 1];
            for (int p = s; p < e2; ++p) srow[p] = (unsigned short)r;
        }
    }
}

// ---------------- K4: edge kernel, one 64-edge tile per block ----------------

__global__ __launch_bounds__(256, 6) void egnn_edge_kernel(
    const float4* __restrict__ pos4,
    const unsigned short* __restrict__ srow_g, const unsigned short* __restrict__ scol_g,
    const unsigned short* __restrict__ a1r, const unsigned short* __restrict__ a1c,
    const float* __restrict__ We1,  // row 128 = dist weights
    const unsigned short* __restrict__ wfrag,
    const float* __restrict__ be2, const float* __restrict__ bc1,
    const float* __restrict__ Wc2, const float* __restrict__ bc2,
    float* __restrict__ msg_agg, float* __restrict__ pos_out)
{
    __shared__ __align__(16) unsigned short sA[64][80];  // [edge][chan]
    __shared__ unsigned short ssr[64];
    __shared__ unsigned short ssc[64];
    __shared__ __align__(16) float4 sdr[64];             // (rx,ry,rz,dsq)
    __shared__ float scw[64];

    const int tid = threadIdx.x;
    const int lane = tid & 63, w = tid >> 6;
    const int li = lane & 15, lg = lane >> 4;
    const int tile = blockIdx.x;
    const int e0 = w * 16;

    // phase 0 (per wave, lanes 0-15): endpoints + relpos for own 16 edges
    if (lane < 16) {
        const int e = e0 + lane;
        const int r = srow_g[tile * 64 + e];
        const int c = scol_g[tile * 64 + e];
        const float4 pr = pos4[r];
        const float4 pc = pos4[c];
        const float rx = pr.x - pc.x, ry = pr.y - pc.y, rz = pr.z - pc.z;
        ssr[e] = (unsigned short)r;
        ssc[e] = (unsigned short)c;
        sdr[e] = make_float4(rx, ry, rz, rx * rx + ry * ry + rz * rz);
    }

    const int c8 = lane & 7;   // channel chunk
    const int eo = lane >> 3;  // edge offset within group of 8

    float w1d8[8];
    {
        const float* wd = We1 + 128 * 64 + c8 * 8;
        const float4 wa = *(const float4*)wd;
        const float4 wb = *(const float4*)(wd + 4);
        w1d8[0] = wa.x; w1d8[1] = wa.y; w1d8[2] = wa.z; w1d8[3] = wa.w;
        w1d8[4] = wb.x; w1d8[5] = wb.y; w1d8[6] = wb.z; w1d8[7] = wb.w;
    }
    float be2v[4], bc1v[4], wc2v[4];
#pragma unroll
    for (int ni = 0; ni < 4; ++ni) {
        be2v[ni] = be2[ni * 16 + li];
        bc1v[ni] = bc1[ni * 16 + li];
        wc2v[ni] = Wc2[ni * 16 + li];
    }
    const float bc2s = bc2[0];

    // phase 2: stage m for own 16 edges (same-wave LDS rows; no barrier needed)
#pragma unroll
    for (int hh = 0; hh < 2; ++hh) {
        const int e = e0 + hh * 8 + eo;
        const int re = ssr[e];
        const int ce = ssc[e];
        const float dv = sdr[e].w;
        const bf16x8 ar = *(const bf16x8*)(a1r + (size_t)re * 64 + c8 * 8);
        const bf16x8 ac = *(const bf16x8*)(a1c + (size_t)ce * 64 + c8 * 8);
        bf16x8 out;
#pragma unroll
        for (int j = 0; j < 8; ++j) {
            const float m = b2f((unsigned short)ar[j]) + b2f((unsigned short)ac[j])
                          + dv * w1d8[j];
            out[j] = (short)f2b(silu_f(m));
        }
        *(bf16x8*)&sA[e][c8 * 8] = out;
    }

    // phase 3: GEMM2 (msg_pre = m @ We2)
    f32x4 acc[4];
#pragma unroll
    for (int ni = 0; ni < 4; ++ni) acc[ni] = (f32x4)(0.0f);
#pragma unroll
    for (int ks = 0; ks < 2; ++ks) {
        const bf16x8 af = *(const bf16x8*)&sA[e0 + li][ks * 32 + (lg << 3)];
#pragma unroll
        for (int ni = 0; ni < 4; ++ni) {
            const bf16x8 bf = *(const bf16x8*)(wfrag + (size_t)(ks * 4 + ni) * 512 + lane * 8);
            acc[ni] = MFMA16(af, bf, acc[ni]);
        }
    }

    // phase 4: msg = silu(msg_pre + be2) -> sA (own rows)
#pragma unroll
    for (int ni = 0; ni < 4; ++ni)
#pragma unroll
        for (int reg = 0; reg < 4; ++reg)
            sA[e0 + lg * 4 + reg][ni * 16 + li] = f2b(silu_f(acc[ni][reg] + be2v[ni]));

    // phase 5: msg quarter-sweep (rows non-decreasing)
    {
        float macc = 0.0f;
        int pr = ssr[e0];
#pragma unroll
        for (int j = 0; j < 16; ++j) {
            const int re = ssr[e0 + j];
            if (re != pr) {
                atomicAdd(&msg_agg[(size_t)pr * 64 + lane], macc);
                macc = 0.0f;
                pr = re;
            }
            macc += b2f(sA[e0 + j][lane]);
        }
        atomicAdd(&msg_agg[(size_t)pr * 64 + lane], macc);
    }

    // phase 6: GEMM3 (t = msg @ Wc1)
    f32x4 a3[4];
#pragma unroll
    for (int ni = 0; ni < 4; ++ni) a3[ni] = (f32x4)(0.0f);
#pragma unroll
    for (int ks = 0; ks < 2; ++ks) {
        const bf16x8 af = *(const bf16x8*)&sA[e0 + li][ks * 32 + (lg << 3)];
#pragma unroll
        for (int ni = 0; ni < 4; ++ni) {
            const bf16x8 bf = *(const bf16x8*)(wfrag + (size_t)(8 + ks * 4 + ni) * 512 + lane * 8);
            a3[ni] = MFMA16(af, bf, a3[ni]);
        }
    }

    // epilogue: cw[edge] = sum_c silu(t+bc1)[c] * Wc2[c]
    float sv[4];
#pragma unroll
    for (int reg = 0; reg < 4; ++reg) {
        float s = 0.0f;
#pragma unroll
        for (int ni = 0; ni < 4; ++ni)
            s += silu_f(a3[ni][reg] + bc1v[ni]) * wc2v[ni];
        sv[reg] = s;
    }
#pragma unroll
    for (int m = 1; m < 16; m <<= 1)
#pragma unroll
        for (int reg = 0; reg < 4; ++reg) sv[reg] += __shfl_xor(sv[reg], m, 64);
    if (li == 0) {
        float4 cv = make_float4(sv[0] + bc2s, sv[1] + bc2s, sv[2] + bc2s, sv[3] + bc2s);
        *(float4*)&scw[e0 + lg * 4] = cv;
    }
    __syncthreads();  // the only block barrier: publishes ssr/sdr/scw to wave 0

    // phase 7: coord aggregation (wave 0): segmented scan, 1 atomic triplet/run
    if (tid < 64) {
        const float4 dr = sdr[tid];
        const int r_e = ssr[tid];
        const float cw = scw[tid];
        float vx = dr.x * cw, vy = dr.y * cw, vz = dr.z * cw;
#pragma unroll
        for (int d = 1; d < 64; d <<= 1) {
            const float ox = __shfl_up(vx, d, 64);
            const float oy = __shfl_up(vy, d, 64);
            const float oz = __shfl_up(vz, d, 64);
            const int   orr = __shfl_up(r_e, d, 64);
            const bool add = (tid >= d) && (orr == r_e);
            vx += add ? ox : 0.0f;
            vy += add ? oy : 0.0f;
            vz += add ? oz : 0.0f;
        }
        const int rnext = __shfl_down(r_e, 1, 64);
        const bool last = (tid == 63) || (rnext != r_e);
        if (last) {
            atomicAdd(&pos_out[r_e * 3 + 0], vx);
            atomicAdd(&pos_out[r_e * 3 + 1], vy);
            atomicAdd(&pos_out[r_e * 3 + 2], vz);
        }
    }
}

// ---------------- K5: node MLP (one 64-node tile per block) ----------------

__global__ __launch_bounds__(256, 4) void node_kernel(
    const float* __restrict__ h, const float* __restrict__ msg_agg,
    const unsigned short* __restrict__ wfrag,
    const float* __restrict__ bn1, const float* __restrict__ bn2,
    float* __restrict__ h_out)
{
    __shared__ __align__(16) unsigned short sA[64][136];
    const int tid = threadIdx.x;
    const int lane = tid & 63, w = tid >> 6;
    const int t = blockIdx.x;
    const int li = lane & 15, lg = lane >> 4;

    float bn1v[4], bn2v[4];
#pragma unroll
    for (int ni = 0; ni < 4; ++ni) {
        bn1v[ni] = bn1[ni * 16 + li];
        bn2v[ni] = bn2[ni * 16 + li];
    }

#pragma unroll
    for (int pass = 0; pass < 8; ++pass) {
        const int idx = pass * 64 + lane;
        const int n_loc = w * 16 + (idx >> 5);
        const int c4 = idx & 31;
        const int n = t * 64 + n_loc;
        float4 v = make_float4(0.f, 0.f, 0.f, 0.f);
        if (n < NN) {
            const float* src = (c4 < 16) ? &h[(size_t)n * 64 + c4 * 4]
                                         : &msg_agg[(size_t)n * 64 + (c4 - 16) * 4];
            v = *(const float4*)src;
        }
        bf16x4 p;
        p[0] = (short)f2b(v.x); p[1] = (short)f2b(v.y);
        p[2] = (short)f2b(v.z); p[3] = (short)f2b(v.w);
        *(bf16x4*)&sA[n_loc][c4 * 4] = p;
    }

    // GEMM1: K=128
    f32x4 acc[4];
#pragma unroll
    for (int ni = 0; ni < 4; ++ni) acc[ni] = (f32x4)(0.0f);
#pragma unroll
    for (int ks = 0; ks < 4; ++ks) {
        const bf16x8 afr = *(const bf16x8*)&sA[w * 16 + li][ks * 32 + (lg << 3)];
#pragma unroll
        for (int ni = 0; ni < 4; ++ni) {
            const bf16x8 bfr = *(const bf16x8*)(wfrag + (size_t)(16 + ks * 4 + ni) * 512 + lane * 8);
            acc[ni] = MFMA16(afr, bfr, acc[ni]);
        }
    }
#pragma unroll
    for (int ni = 0; ni < 4; ++ni)
#pragma unroll
        for (int reg = 0; reg < 4; ++reg)
            sA[w * 16 + lg * 4 + reg][ni * 16 + li] = f2b(silu_f(acc[ni][reg] + bn1v[ni]));

    // GEMM2: K=64
    f32x4 a2[4];
#pragma unroll
    for (int ni = 0; ni < 4; ++ni) a2[ni] = (f32x4)(0.0f);
#pragma unroll
    for (int ks = 0; ks < 2; ++ks) {
        const bf16x8 afr = *(const bf16x8*)&sA[w * 16 + li][ks * 32 + (lg << 3)];
#pragma unroll
        for (int ni = 0; ni < 4; ++ni) {
            const bf16x8 bfr = *(const bf16x8*)(wfrag + (size_t)(32 + ks * 4 + ni) * 512 + lane * 8);
            a2[ni] = MFMA16(afr, bfr, a2[ni]);
        }
    }
#pragma unroll
    for (int ni = 0; ni < 4; ++ni)
#pragma unroll
        for (int reg = 0; reg < 4; ++reg) {
            const int n = t * 64 + w * 16 + lg * 4 + reg;
            if (n < NN) h_out[(size_t)n * 64 + ni * 16 + li] = a2[ni][reg] + bn2v[ni];
        }
}

// ---------------- launch ----------------

extern "C" void kernel_launch(void* const* d_in, const int* in_sizes, int n_in,
                              void* d_out, int out_size, void* d_ws, size_t ws_size,
                              hipStream_t stream) {
    const float* h   = (const float*)d_in[0];
    const float* pos = (const float*)d_in[1];
    const int*   ei  = (const int*)d_in[2];
    const float* We1 = (const float*)d_in[3];
    const float* be1 = (const float*)d_in[4];
    const float* We2 = (const float*)d_in[5];
    const float* be2 = (const float*)d_in[6];
    const float* Wc1 = (const float*)d_in[7];
    const float* bc1 = (const float*)d_in[8];
    const float* Wc2 = (const float*)d_in[9];
    const float* bc2 = (const float*)d_in[10];
    const float* Wn1 = (const float*)d_in[11];
    const float* bn1 = (const float*)d_in[12];
    const float* Wn2 = (const float*)d_in[13];
    const float* bn2 = (const float*)d_in[14];

    // workspace layout (~17.4 MB)
    char* ws = (char*)d_ws;
    unsigned short* a1r    = (unsigned short*)(ws);              // 6,400,000 B
    unsigned short* a1c    = (unsigned short*)(ws + 6400000);    // 6,400,000 B
    unsigned short* wfrag  = (unsigned short*)(ws + 12800000);   // 56*512*2 = 57,344 B
    unsigned short* scol   = (unsigned short*)(ws + 12857344);   // 1,600,000 B
    unsigned short* srow   = (unsigned short*)(ws + 14457344);   // 1,600,000 B
    int*            cursor = (int*)(ws + 16057344);              // 53248*4 = 212,992 B
    int*            row_ptr= (int*)(ws + 16270336);              // 50016*4 B
    float4*         pos4   = (float4*)(ws + 16470400);           // 800,000 B

    float* msg_agg = (float*)d_out;                              // reused as h_out
    float* pos_out = msg_agg + (size_t)NN * 64;

    hipMemsetAsync(cursor, 0, (size_t)SCAN_PAD * sizeof(int), stream);
    prep1_kernel<<<K1_GRID, 256, 0, stream>>>(ei, pos, We1, We2, Wc1, Wn1, Wn2,
                                              wfrag, cursor, msg_agg, pos_out, pos4);
    scan_kernel<<<1, 1024, 0, stream>>>(cursor, row_ptr);
    prep2_kernel<<<K3_GRID, 256, 0, stream>>>(h, be1, ei, cursor, row_ptr, wfrag,
                                              a1r, a1c, scol, srow);
    egnn_edge_kernel<<<ETILE, 256, 0, stream>>>(pos4, srow, scol, a1r, a1c, We1, wfrag,
                                                be2, bc1, Wc2, bc2, msg_agg, pos_out);
    node_kernel<<<NTILE, 256, 0, stream>>>(h, msg_agg, wfrag, bn1, bn2, msg_agg);
}